// Round 10
// baseline (213.458 us; speedup 1.0000x reference)
//
#include <hip/hip_runtime.h>
#include <hip/hip_bf16.h>
#include <stdint.h>

// out[b,n,o] = sum_t x[b,n,t] * (sum_g y[b,g]*w[g,o,t]*mask[o,t]) + bias[o]
// B=32 N=256 T=1024 O=1024 G=8.  bf16 MFMA path (absmax 0.031 vs thr 0.154).
//
// R10: STRUCTURAL — Wb is no longer materialized (was 82 MB HBM write + 134 MB
// re-read).  K1 converts x->bf16 only.  K2 fuses the genre-mix into the GEMM:
// each block (o-tile 64, batch b) mixes its W-tile from w/mask/y in registers
// and ds_writes it (bf16, XOR-swizzled) into LDS, while xb stages via
// global_load_lds; then 32x32x16 MFMA (layouts verified R9/m74/m101).
// Grid laid out so XCD = blockIdx%8 = otile%8: all 32 b-blocks of an o-tile
// share one XCD's L2 for their w slice (8g x 64 rows x 4KB x 2 otiles = 4 MB).

#define B_ 32
#define N_ 256
#define T_ 1024
#define O_ 1024
#define G_ 8

#define BM 256           // n rows per block (= all of N)
#define BN 64            // o cols per block
#define BK 64            // k chunk; LDS row = 128 B = 8 x 16 B chunks

typedef __attribute__((__ext_vector_type__(8)))  __bf16 bf16x8;
typedef __attribute__((__ext_vector_type__(16))) float  f32x16;

__device__ __forceinline__ unsigned short f2bf(float f) {
    union { float f; uint32_t u; } v; v.f = f;
    uint32_t u = v.u;
    uint32_t r = (u + 0x7fffu + ((u >> 16) & 1u)) >> 16;  // RNE
    return (unsigned short)r;
}

__device__ __forceinline__ uint4 pack8(const float* a) {
    uint4 r;
    r.x = (uint32_t)f2bf(a[0]) | ((uint32_t)f2bf(a[1]) << 16);
    r.y = (uint32_t)f2bf(a[2]) | ((uint32_t)f2bf(a[3]) << 16);
    r.z = (uint32_t)f2bf(a[4]) | ((uint32_t)f2bf(a[5]) << 16);
    r.w = (uint32_t)f2bf(a[6]) | ((uint32_t)f2bf(a[7]) << 16);
    return r;
}

#define CVTB 1024   // 262144 threads, 8 float4 each

// --- K1: x f32 -> bf16 (pure streaming).
__global__ __launch_bounds__(256) void cvt_kernel(
    const float* __restrict__ x, unsigned short* __restrict__ xb)
{
    const int i = blockIdx.x * 256 + threadIdx.x;
    const float4* x4 = (const float4*)x;
    uint4* o4 = (uint4*)xb;
#pragma unroll
    for (int j = 0; j < 4; ++j) {
        const size_t f4 = (size_t)j * 524288 + (size_t)i * 2;
        const float4 a = x4[f4];
        const float4 b = x4[f4 + 1];
        const float v[8] = {a.x, a.y, a.z, a.w, b.x, b.y, b.z, b.w};
        o4[(size_t)j * 262144 + i] = pack8(v);
    }
}

__device__ __forceinline__ void load16_to_lds(const unsigned short* g, unsigned short* l) {
    __builtin_amdgcn_global_load_lds(
        (const __attribute__((address_space(1))) unsigned char*)g,
        (__attribute__((address_space(3))) unsigned char*)l,
        16, 0, 0);
}

// --- K2: fused mix+GEMM.  256 thr / 4 waves, wave tile 64x64 (2x2 of 32x32).
// LDS chunk c of row r holds global chunk (c ^ (r&7)) on BOTH tiles:
// A-side enforced by lane-contiguous global_load_lds source swizzle,
// B-side applied at ds_write.  ds_read_b128 phases then hit all 8 bank
// groups 2-way (free, m136); the mix ds_writes are 2-way as well.
__global__ __launch_bounds__(256, 2) void fused_kernel(
    const unsigned short* __restrict__ xb,   // [B][N_][T_] bf16
    const float* __restrict__ w,             // [G,O,T]
    const float* __restrict__ mask,          // [O,T]
    const float* __restrict__ y,             // [B,G]
    const float* __restrict__ bias,          // [O_]
    float* __restrict__ out)                 // [B][N_][O_] f32
{
    __shared__ __align__(16) unsigned short lA[BM * BK];  // 32 KiB
    __shared__ __align__(16) unsigned short lB[BN * BK];  // 8 KiB

    const int bx = blockIdx.x;
    const int ot = bx & 15;        // o tile 0..15 -> XCD = bx%8 = ot%8
    const int b  = bx >> 4;        // 0..31

    const int tid  = threadIdx.x;
    const int lane = tid & 63;
    const int wave = tid >> 6;     // 0..3
    const int wm   = wave * 64;    // m offset; wn = 0 (BN=64 handled by ni loop)

    // A staging: round r8: LDS elem tid*8 + r8*2048 -> row tid/8 + r8*32, chunk tid&7
    const int srow   = tid >> 3;                 // 0..31
    const int schunk = (tid & 7) ^ (srow & 7);   // (r8*32)&7==0 -> round-invariant
    const unsigned short* gA =
        xb + (size_t)b * N_ * T_ + (size_t)srow * T_ + schunk * 8;

    // W-mix mapping: thread -> row mr (0..63), chunk pair mcp (0..3)
    const int mr  = tid >> 2;
    const int mcp = tid & 3;
    const int mo  = ot * BN + mr;
    const float* mp  = mask + (size_t)mo * T_;
    const float* wp0 = w + (size_t)mo * T_;
    float yv[G_];
#pragma unroll
    for (int g = 0; g < G_; ++g) yv[g] = y[b * G_ + g];

    f32x16 acc[2][2] = {};

    const int fr   = lane & 31;    // fragment row within 32
    const int half = lane >> 5;    // k-half 0/1
    const int sw   = fr & 7;

    for (int kt = 0; kt < T_; kt += BK) {
        // A: async DMA (issued first so it overlaps the mix VALU below)
#pragma unroll
        for (int r8 = 0; r8 < 8; ++r8)
            load16_to_lds(gA + kt + (size_t)(r8 * 32) * T_, lA + tid * 8 + r8 * 2048);

        // B: mix 2 chunks of 8 k for row mr
#pragma unroll
        for (int cc = 0; cc < 2; ++cc) {
            const int c  = 2 * mcp + cc;
            const int gk = kt + c * 8;
            const float4 ma = *(const float4*)(mp + gk);
            const float4 mb = *(const float4*)(mp + gk + 4);
            float a8[8] = {};
#pragma unroll
            for (int g = 0; g < G_; ++g) {
                const float* wp = wp0 + (size_t)g * O_ * T_ + gk;
                const float4 wa = *(const float4*)(wp);
                const float4 wb = *(const float4*)(wp + 4);
                a8[0] += yv[g] * wa.x; a8[1] += yv[g] * wa.y;
                a8[2] += yv[g] * wa.z; a8[3] += yv[g] * wa.w;
                a8[4] += yv[g] * wb.x; a8[5] += yv[g] * wb.y;
                a8[6] += yv[g] * wb.z; a8[7] += yv[g] * wb.w;
            }
            a8[0] *= ma.x; a8[1] *= ma.y; a8[2] *= ma.z; a8[3] *= ma.w;
            a8[4] *= mb.x; a8[5] *= mb.y; a8[6] *= mb.z; a8[7] *= mb.w;
            *(uint4*)(lB + mr * BK + ((c ^ (mr & 7)) * 8)) = pack8(a8);
        }

        __syncthreads();   // A DMA drained (vmcnt) + B writes visible

#pragma unroll
        for (int ks = 0; ks < 4; ++ks) {
            const int cp = ((ks * 2 + half) ^ sw) * 8;
            bf16x8 afr[2], bfr[2];
#pragma unroll
            for (int i_ = 0; i_ < 2; ++i_)
                afr[i_] = *(const bf16x8*)(lA + (wm + i_ * 32 + fr) * BK + cp);
#pragma unroll
            for (int i_ = 0; i_ < 2; ++i_)
                bfr[i_] = *(const bf16x8*)(lB + (i_ * 32 + fr) * BK + cp);
#pragma unroll
            for (int mi = 0; mi < 2; ++mi)
#pragma unroll
                for (int ni = 0; ni < 2; ++ni)
                    acc[mi][ni] = __builtin_amdgcn_mfma_f32_32x32x16_bf16(
                        afr[mi], bfr[ni], acc[mi][ni], 0, 0, 0);
        }

        __syncthreads();   // all reads done before next chunk overwrites
    }

    // Epilogue: D col=lane&31, row=(reg&3)+8*(reg>>2)+4*(lane>>5) (m74/m101, R9-verified)
    float* outb = out + (size_t)b * N_ * O_ + (ot * BN);
    const int cn = lane & 31;
    const int rb = (lane >> 5) * 4;
#pragma unroll
    for (int ni = 0; ni < 2; ++ni) {
        const int col = ni * 32 + cn;
        const float bv = bias[ot * BN + col];
#pragma unroll
        for (int mi = 0; mi < 2; ++mi) {
#pragma unroll
            for (int r = 0; r < 16; ++r) {
                const int row = wm + mi * 32 + rb + (r & 3) + 8 * (r >> 2);
                outb[(size_t)row * O_ + col] = acc[mi][ni][r] + bv;
            }
        }
    }
}

// --- Fallback (ws too small): correct fp32 path.
__global__ __launch_bounds__(256) void naive_kernel(
    const float* __restrict__ x, const float* __restrict__ y,
    const float* __restrict__ w, const float* __restrict__ mask,
    const float* __restrict__ bias, float* __restrict__ out)
{
    const int oc = blockIdx.x & 3;
    const int n  = (blockIdx.x >> 2) & (N_ - 1);
    const int b  = blockIdx.x >> 10;

    __shared__ float xs[T_];
    __shared__ float ys[G_];
    const float* xrow = x + ((size_t)b * N_ + n) * T_;
    for (int i = threadIdx.x; i < T_ / 4; i += 256)
        ((float4*)xs)[i] = ((const float4*)xrow)[i];
    if (threadIdx.x < G_) ys[threadIdx.x] = y[b * G_ + threadIdx.x];
    __syncthreads();

    const int o = oc * 256 + threadIdx.x;
    float acc = 0.f;
    for (int t = 0; t < T_; t += 4) {
        const float4 m4 = *(const float4*)(mask + (size_t)o * T_ + t);
        float4 s = {0.f, 0.f, 0.f, 0.f};
#pragma unroll
        for (int g = 0; g < G_; ++g) {
            const float4 w4 = *(const float4*)(w + ((size_t)g * O_ + o) * T_ + t);
            const float yv = ys[g];
            s.x += yv * w4.x; s.y += yv * w4.y; s.z += yv * w4.z; s.w += yv * w4.w;
        }
        acc += xs[t] * m4.x * s.x + xs[t + 1] * m4.y * s.y
             + xs[t + 2] * m4.z * s.z + xs[t + 3] * m4.w * s.w;
    }
    out[((size_t)b * N_ + n) * O_ + o] = acc + bias[o];
}

extern "C" void kernel_launch(void* const* d_in, const int* in_sizes, int n_in,
                              void* d_out, int out_size, void* d_ws, size_t ws_size,
                              hipStream_t stream) {
    const float* x    = (const float*)d_in[0];
    const float* y    = (const float*)d_in[1];
    const float* w    = (const float*)d_in[2];
    const float* mask = (const float*)d_in[3];
    const float* bias = (const float*)d_in[4];
    float* out = (float*)d_out;

    const size_t xb_bytes = (size_t)B_ * N_ * T_ * sizeof(unsigned short); // 16 MiB

    if (ws_size >= xb_bytes) {
        unsigned short* xb = (unsigned short*)d_ws;
        cvt_kernel<<<CVTB, 256, 0, stream>>>(x, xb);
        fused_kernel<<<(O_ / BN) * B_, 256, 0, stream>>>(xb, w, mask, y, bias, out);
    } else {
        naive_kernel<<<B_ * N_ * (O_ / 256), 256, 0, stream>>>(x, y, w, mask, bias, out);
    }
}